// Round 5
// baseline (19.720 us; speedup 1.0000x reference)
//
#include <hip/hip_runtime.h>
#include <hip/hip_bf16.h>

#define Bc 32
#define Lc 2048
#define Hc 768
#define Dc 32
#define Cc 64
#define WAVES 4
#define TPB (WAVES * 64)

// One block (256 threads = 4 waves) per (b, d) clause. Single pass, online
// softmax, 2 rows per step, 2 pairs prefetched (depth-2 pipeline). All 1024
// blocks resident (4 blocks/CU): 12.4 KB LDS, VGPR capped at 128.
__global__ __launch_bounds__(TPB, 4) void clause_attn_fused(
    const float* __restrict__ hs,         // [B, L, H]
    const float* __restrict__ fc_w,       // [H]
    const int*   __restrict__ clause_len, // [B, D]
    const int*   __restrict__ doc_len,    // [B]
    float*       __restrict__ out)        // [B, D, H]
{
    const int bd   = blockIdx.x;
    const int b    = bd >> 5;     // / Dc
    const int d    = bd & 31;     // % Dc
    const int tid  = threadIdx.x;
    const int lane = tid & 63;
    const int wave = tid >> 6;

    __shared__ float s_m[WAVES];
    __shared__ float s_s[WAVES];
    __shared__ float s_acc[WAVES][Hc];   // 12 KB
    __shared__ int   s_n, s_off;

    // Wave 0: exclusive prefix sum of clause_len[b, :] (lanes 0..31).
    if (wave == 0) {
        int v = (lane < Dc) ? clause_len[b * Dc + lane] : 0;
        int sum = v;
        #pragma unroll
        for (int s = 1; s < 32; s <<= 1) {
            int o = __shfl_up(sum, s, 64);
            if (lane >= s) sum += o;
        }
        if (lane == d) {
            s_off = sum - v;                       // exclusive offset
            s_n   = (d < doc_len[b]) ? v : 0;      // valid-token count
        }
    }
    __syncthreads();

    const int n   = s_n;
    const int off = s_off;
    float* ob = out + (size_t)bd * Hc;

    if (n == 0) {
        // Fully-masked clause: reference = uniform weights x zeroed sent = 0.
        ob[tid] = 0.0f; ob[tid + 256] = 0.0f; ob[tid + 512] = 0.0f;
        return;
    }

    // fc_w in registers: lane owns h = chunk*256 + lane*4 + j.
    const int hbase = lane * 4;
    const float4 w0 = *(const float4*)(fc_w + hbase);
    const float4 w1 = *(const float4*)(fc_w + 256 + hbase);
    const float4 w2 = *(const float4*)(fc_w + 512 + hbase);

    const float* base = hs + (size_t)b * Lc * Hc;
    const float4 z4 = {0.f, 0.f, 0.f, 0.f};
    // off + n - 1 <= 2016 < Lc, so no clamping needed for valid slots.

    #define LOADROW(c, x0, x1, x2)                                      \
        if ((c) < n) {                                                  \
            const float* r_ = base + (size_t)(off + (c)) * Hc + hbase;  \
            x0 = *(const float4*)(r_);                                  \
            x1 = *(const float4*)(r_ + 256);                            \
            x2 = *(const float4*)(r_ + 512);                            \
        } else { x0 = z4; x1 = z4; x2 = z4; }

    float m = -INFINITY, ssum = 0.0f;
    float4 a0 = z4, a1 = z4, a2 = z4;

    // Pipeline: pair(c) = rows (c, c+4); pairs at stride 8 per wave.
    float4 A00, A01, A02, A10, A11, A12;   // compute pair
    float4 B00, B01, B02, B10, B11, B12;   // prefetch depth 1
    int c = wave;
    LOADROW(c,     A00, A01, A02);
    LOADROW(c + 4, A10, A11, A12);
    LOADROW(c + 8,  B00, B01, B02);
    LOADROW(c + 12, B10, B11, B12);

    for (; c < n; c += 8) {
        // Prefetch depth 2: pair(c+16).
        float4 C00, C01, C02, C10, C11, C12;
        LOADROW(c + 16, C00, C01, C02);
        LOADROW(c + 20, C10, C11, C12);

        // Two interleaved dot products (row c always valid; row c+4 maybe not).
        float p0 = A00.x*w0.x + A00.y*w0.y + A00.z*w0.z + A00.w*w0.w
                 + A01.x*w1.x + A01.y*w1.y + A01.z*w1.z + A01.w*w1.w
                 + A02.x*w2.x + A02.y*w2.y + A02.z*w2.z + A02.w*w2.w;
        float p1 = A10.x*w0.x + A10.y*w0.y + A10.z*w0.z + A10.w*w0.w
                 + A11.x*w1.x + A11.y*w1.y + A11.z*w1.z + A11.w*w1.w
                 + A12.x*w2.x + A12.y*w2.y + A12.z*w2.z + A12.w*w2.w;
        #pragma unroll
        for (int s = 32; s > 0; s >>= 1) {
            p0 += __shfl_xor(p0, s, 64);
            p1 += __shfl_xor(p1, s, 64);
        }
        if (c + 4 >= n) p1 = -INFINITY;    // masked row: e1 = 0, data already 0

        // Combined 2-row online-softmax update.
        const float M     = fmaxf(m, fmaxf(p0, p1));   // v_max3
        const float scale = __expf(m - M);             // first pair: exp(-inf)=0
        const float e0    = __expf(p0 - M);
        const float e1    = __expf(p1 - M);
        ssum = ssum * scale + e0 + e1;
        a0.x = fmaf(e1, A10.x, fmaf(e0, A00.x, a0.x * scale));
        a0.y = fmaf(e1, A10.y, fmaf(e0, A00.y, a0.y * scale));
        a0.z = fmaf(e1, A10.z, fmaf(e0, A00.z, a0.z * scale));
        a0.w = fmaf(e1, A10.w, fmaf(e0, A00.w, a0.w * scale));
        a1.x = fmaf(e1, A11.x, fmaf(e0, A01.x, a1.x * scale));
        a1.y = fmaf(e1, A11.y, fmaf(e0, A01.y, a1.y * scale));
        a1.z = fmaf(e1, A11.z, fmaf(e0, A01.z, a1.z * scale));
        a1.w = fmaf(e1, A11.w, fmaf(e0, A01.w, a1.w * scale));
        a2.x = fmaf(e1, A12.x, fmaf(e0, A02.x, a2.x * scale));
        a2.y = fmaf(e1, A12.y, fmaf(e0, A02.y, a2.y * scale));
        a2.z = fmaf(e1, A12.z, fmaf(e0, A02.z, a2.z * scale));
        a2.w = fmaf(e1, A12.w, fmaf(e0, A02.w, a2.w * scale));
        m = M;

        // Rotate pipeline.
        A00 = B00; A01 = B01; A02 = B02; A10 = B10; A11 = B11; A12 = B12;
        B00 = C00; B01 = C01; B02 = C02; B10 = C10; B11 = C11; B12 = C12;
    }
    #undef LOADROW

    // Publish per-wave partial state.
    if (lane == 0) { s_m[wave] = m; s_s[wave] = ssum; }
    *(float4*)&s_acc[wave][hbase]       = a0;
    *(float4*)&s_acc[wave][256 + hbase] = a1;
    *(float4*)&s_acc[wave][512 + hbase] = a2;
    __syncthreads();

    // Merge 4 partials. n >= 1 so wave 0 contributed -> M finite, S > 0.
    float M = -INFINITY;
    #pragma unroll
    for (int w = 0; w < WAVES; ++w) M = fmaxf(M, s_m[w]);
    float f[WAVES];
    float S = 0.0f;
    #pragma unroll
    for (int w = 0; w < WAVES; ++w) {
        f[w] = __expf(s_m[w] - M);           // idle wave: exp(-inf) = 0
        S += f[w] * s_s[w];
    }
    const float rinv = 1.0f / S;

    #pragma unroll
    for (int chunk = 0; chunk < 3; ++chunk) {
        const int h = chunk * TPB + tid;
        float r = 0.0f;
        #pragma unroll
        for (int w = 0; w < WAVES; ++w) r += f[w] * s_acc[w][h];
        ob[h] = r * rinv;
    }
}

extern "C" void kernel_launch(void* const* d_in, const int* in_sizes, int n_in,
                              void* d_out, int out_size, void* d_ws, size_t ws_size,
                              hipStream_t stream) {
    const float* hs         = (const float*)d_in[0];  // [B, L, H]
    const float* fc_w       = (const float*)d_in[1];  // [H]
    // d_in[2] = fc_b — constant across the softmax axis, cancels exactly.
    const int*   clause_len = (const int*)d_in[3];    // [B, D]
    const int*   doc_len    = (const int*)d_in[4];    // [B]
    float*       out        = (float*)d_out;          // [B, D, H]

    clause_attn_fused<<<Bc * Dc, TPB, 0, stream>>>(hs, fc_w, clause_len, doc_len, out);
}